// Round 1
// baseline (632.003 us; speedup 1.0000x reference)
//
#include <hip/hip_runtime.h>
#include <math.h>

#define NN 50000      // nodes
#define NE 800000     // edges
#define NB 4          // batch
#define C  64         // channels (C_IN == C_OUT)
#define EF 10
#define EH 4

__device__ __forceinline__ float lrelu(float x, float s) { return x > 0.f ? x : s * x; }

// ---------------- edge MLP -> scalar aE, plus per-dst sum/count for self-loop mean
__global__ void edge_mlp_kernel(const float* __restrict__ edge_attr,
                                const int* __restrict__ edge_index,
                                const float* __restrict__ W1,
                                const float* __restrict__ W2,
                                const float* __restrict__ linW,
                                const float* __restrict__ attE,
                                float* __restrict__ aE,
                                float* __restrict__ sumA,
                                int* __restrict__ cnt) {
    // uniform: v[h] = linW[h]·attE ; u[g] = W2[g]·v  (compiler keeps these scalar-cached)
    float v[EH];
#pragma unroll
    for (int h = 0; h < EH; h++) {
        float s = 0.f;
        for (int c = 0; c < C; c++) s += linW[h * C + c] * attE[c];
        v[h] = s;
    }
    float u[EH];
#pragma unroll
    for (int g = 0; g < EH; g++) {
        float s = 0.f;
#pragma unroll
        for (int h = 0; h < EH; h++) s += W2[g * EH + h] * v[h];
        u[g] = s;
    }
    int e = blockIdx.x * blockDim.x + threadIdx.x;
    if (e >= NE) return;
    const float* ea = edge_attr + (size_t)e * EF;
    float a = 0.f;
#pragma unroll
    for (int h = 0; h < EH; h++) {
        float s = 0.f;
#pragma unroll
        for (int f = 0; f < EF; f++) s += ea[f] * W1[f * EH + h];
        a += lrelu(s, 0.01f) * u[h];
    }
    aE[e] = a;
    int d = edge_index[NE + e];
    atomicAdd(&sumA[d], a);
    atomicAdd(&cnt[d], 1);
}

__global__ void aloop_kernel(const float* __restrict__ sumA, const int* __restrict__ cnt,
                             float* __restrict__ a_loop) {
    int n = blockIdx.x * blockDim.x + threadIdx.x;
    if (n < NN) a_loop[n] = sumA[n] / fmaxf((float)cnt[n], 1.0f);
}

// ---------------- two-level exclusive scan of cnt -> rowptr[N+1]
__global__ void scan_block_kernel(const int* __restrict__ cnt, int* __restrict__ rowptr,
                                  int* __restrict__ bsum) {
    __shared__ int sh[1024];
    int i = blockIdx.x * 1024 + threadIdx.x;
    sh[threadIdx.x] = (i < NN) ? cnt[i] : 0;
    __syncthreads();
    for (int off = 1; off < 1024; off <<= 1) {
        int t = (threadIdx.x >= (unsigned)off) ? sh[threadIdx.x - off] : 0;
        __syncthreads();
        sh[threadIdx.x] += t;
        __syncthreads();
    }
    if (i < NN) rowptr[1 + i] = sh[threadIdx.x];
    if (threadIdx.x == 1023) bsum[blockIdx.x] = sh[1023];
}

__global__ void scan_sums_kernel(int* __restrict__ bsum, int nb) {
    int lane = threadIdx.x;
    int v = (lane < nb) ? bsum[lane] : 0;
    int orig = v;
    for (int off = 1; off < 64; off <<= 1) {
        int t = __shfl_up(v, off);
        if (lane >= off) v += t;
    }
    if (lane < nb) bsum[lane] = v - orig;  // exclusive
}

__global__ void scan_add_kernel(int* __restrict__ rowptr, const int* __restrict__ bsum) {
    int i = blockIdx.x * blockDim.x + threadIdx.x;
    if (i < NN) rowptr[1 + i] += bsum[i >> 10];
    if (i == 0) rowptr[0] = 0;
}

__global__ void scatter_kernel(const int* __restrict__ edge_index, const float* __restrict__ aE,
                               const int* __restrict__ rowptr, int* __restrict__ wcount,
                               int* __restrict__ csr_src, float* __restrict__ csr_aE) {
    int e = blockIdx.x * blockDim.x + threadIdx.x;
    if (e >= NE) return;
    int s = edge_index[e];
    int d = edge_index[NE + e];
    int pos = atomicAdd(&wcount[d], 1);
    int idx = rowptr[d] + pos;
    csr_src[idx] = s;
    csr_aE[idx] = aE[e];
}

// ---------------- h = x@W, a_s = h·att_src, a_d = h·att_dst   (one wave per (b,n))
__global__ void nodeprep_kernel(const float* __restrict__ x, const float* __restrict__ W,
                                const float* __restrict__ att_src, const float* __restrict__ att_dst,
                                float* __restrict__ h, float* __restrict__ a_s,
                                float* __restrict__ a_d) {
    __shared__ float Wl[C * C];
    for (int i = threadIdx.x; i < C * C; i += blockDim.x) Wl[i] = W[i];
    __syncthreads();
    int wid = blockIdx.x * (blockDim.x >> 6) + (threadIdx.x >> 6);
    if (wid >= NB * NN) return;
    int lane = threadIdx.x & 63;
    float xv = x[(size_t)wid * C + lane];
    float hc = 0.f;
#pragma unroll
    for (int k = 0; k < C; k++) {
        float xk = __shfl(xv, k);
        hc += xk * Wl[k * C + lane];
    }
    h[(size_t)wid * C + lane] = hc;
    float ps = hc * att_src[lane];
    float pd = hc * att_dst[lane];
    for (int off = 32; off; off >>= 1) {
        ps += __shfl_xor(ps, off);
        pd += __shfl_xor(pd, off);
    }
    if (lane == 0) {
        a_s[wid] = ps;
        a_d[wid] = pd;
    }
}

// ---------------- per-(b,n) softmax + weighted gather, one wave per (b,n)
__global__ void gather_kernel(const int* __restrict__ rowptr, const int* __restrict__ csr_src,
                              const float* __restrict__ csr_aE, const float* __restrict__ a_s,
                              const float* __restrict__ a_d, const float* __restrict__ a_loop,
                              const float* __restrict__ h, const float* __restrict__ bias,
                              float* __restrict__ out) {
    int wid = blockIdx.x * (blockDim.x >> 6) + (threadIdx.x >> 6);
    if (wid >= NB * NN) return;
    int lane = threadIdx.x & 63;
    int b = wid / NN;
    int n = wid - b * NN;
    int r0 = rowptr[n], r1 = rowptr[n + 1];
    int deg = r1 - r0;
    const float* asb = a_s + (size_t)b * NN;
    float adst = a_d[(size_t)b * NN + n];
    float l_loop = lrelu(asb[n] + adst + a_loop[n], 0.2f);

    // sweep 1: max
    float mx = l_loop;
    for (int base = 0; base < deg; base += 64) {
        int j = base + lane;
        float lg = -INFINITY;
        if (j < deg) {
            int s = csr_src[r0 + j];
            lg = lrelu(asb[s] + adst + csr_aE[r0 + j], 0.2f);
        }
        mx = fmaxf(mx, lg);
    }
    for (int off = 32; off; off >>= 1) mx = fmaxf(mx, __shfl_xor(mx, off));

    // sweep 2: denom
    float ds = 0.f;
    for (int base = 0; base < deg; base += 64) {
        int j = base + lane;
        if (j < deg) {
            int s = csr_src[r0 + j];
            float lg = lrelu(asb[s] + adst + csr_aE[r0 + j], 0.2f);
            ds += __expf(lg - mx);
        }
    }
    for (int off = 32; off; off >>= 1) ds += __shfl_xor(ds, off);
    float eloop = __expf(l_loop - mx);
    ds += eloop;
    float inv = 1.0f / ds;

    // sweep 3: weighted accumulate (coalesced 256B h-row per edge)
    const float* hb = h + (size_t)b * NN * C;
    float acc = eloop * inv * hb[(size_t)n * C + lane];
    for (int base = 0; base < deg; base += 64) {
        int j = base + lane;
        int cn = min(64, deg - base);
        float ex = 0.f;
        int s = 0;
        if (j < deg) {
            s = csr_src[r0 + j];
            float lg = lrelu(asb[s] + adst + csr_aE[r0 + j], 0.2f);
            ex = __expf(lg - mx) * inv;
        }
        for (int jj = 0; jj < cn; jj++) {
            float al = __shfl(ex, jj);
            int sj = __shfl(s, jj);
            acc += al * hb[(size_t)sj * C + lane];
        }
    }
    acc += bias[lane];
    out[(size_t)wid * C + lane] = acc > 0.f ? acc : __expf(acc) - 1.f;
}

extern "C" void kernel_launch(void* const* d_in, const int* in_sizes, int n_in,
                              void* d_out, int out_size, void* d_ws, size_t ws_size,
                              hipStream_t stream) {
    const float* x      = (const float*)d_in[0];
    const int* eidx     = (const int*)d_in[1];
    const float* eattr  = (const float*)d_in[2];
    const float* W1     = (const float*)d_in[3];
    const float* W2     = (const float*)d_in[4];
    const float* W      = (const float*)d_in[5];
    const float* linW   = (const float*)d_in[6];
    const float* attS   = (const float*)d_in[7];
    const float* attD   = (const float*)d_in[8];
    const float* attE   = (const float*)d_in[9];
    const float* bias   = (const float*)d_in[10];
    float* out = (float*)d_out;

    size_t off = 0;
    auto alloc = [&](size_t bytes) {
        void* p = (char*)d_ws + off;
        off += (bytes + 255) / 256 * 256;
        return p;
    };
    float* aE     = (float*)alloc((size_t)NE * 4);
    float* sumA   = (float*)alloc((size_t)NN * 4);
    int* cnt      = (int*)alloc((size_t)NN * 4);
    int* wcount   = (int*)alloc((size_t)NN * 4);
    float* a_loop = (float*)alloc((size_t)NN * 4);
    int* rowptr   = (int*)alloc((size_t)(NN + 1) * 4);
    int* bsum     = (int*)alloc(64 * 4);
    int* csr_src  = (int*)alloc((size_t)NE * 4);
    float* csr_aE = (float*)alloc((size_t)NE * 4);
    float* h      = (float*)alloc((size_t)NB * NN * C * 4);
    float* a_s    = (float*)alloc((size_t)NB * NN * 4);
    float* a_d    = (float*)alloc((size_t)NB * NN * 4);
    (void)ws_size; (void)n_in; (void)in_sizes; (void)out_size;

    hipMemsetAsync(sumA, 0, (size_t)NN * 4, stream);
    hipMemsetAsync(cnt, 0, (size_t)NN * 4, stream);
    hipMemsetAsync(wcount, 0, (size_t)NN * 4, stream);

    edge_mlp_kernel<<<(NE + 255) / 256, 256, 0, stream>>>(eattr, eidx, W1, W2, linW, attE,
                                                          aE, sumA, cnt);
    aloop_kernel<<<(NN + 255) / 256, 256, 0, stream>>>(sumA, cnt, a_loop);

    int nblk = (NN + 1023) / 1024;  // 49
    scan_block_kernel<<<nblk, 1024, 0, stream>>>(cnt, rowptr, bsum);
    scan_sums_kernel<<<1, 64, 0, stream>>>(bsum, nblk);
    scan_add_kernel<<<(NN + 1023) / 1024, 1024, 0, stream>>>(rowptr, bsum);

    scatter_kernel<<<(NE + 255) / 256, 256, 0, stream>>>(eidx, aE, rowptr, wcount,
                                                         csr_src, csr_aE);

    nodeprep_kernel<<<(NB * NN + 3) / 4, 256, 0, stream>>>(x, W, attS, attD, h, a_s, a_d);

    gather_kernel<<<(NB * NN + 3) / 4, 256, 0, stream>>>(rowptr, csr_src, csr_aE,
                                                         a_s, a_d, a_loop, h, bias, out);
}

// Round 2
// 506.965 us; speedup vs baseline: 1.2466x; 1.2466x over previous
//
#include <hip/hip_runtime.h>
#include <math.h>

#define NN 50000      // nodes
#define NE 800000     // edges
#define NB 4          // batch
#define C  64         // channels (C_IN == C_OUT)
#define EF 10
#define EH 4

__device__ __forceinline__ float lrelu(float x, float s) { return x > 0.f ? x : s * x; }

// ---------------- degree histogram
__global__ void degree_kernel(const int* __restrict__ edge_index, int* __restrict__ cnt) {
    int e = blockIdx.x * blockDim.x + threadIdx.x;
    if (e < NE) atomicAdd(&cnt[edge_index[NE + e]], 1);
}

// ---------------- two-level exclusive scan of cnt -> rowptr[N+1]
__global__ void scan_block_kernel(const int* __restrict__ cnt, int* __restrict__ rowptr,
                                  int* __restrict__ bsum) {
    __shared__ int sh[1024];
    int i = blockIdx.x * 1024 + threadIdx.x;
    sh[threadIdx.x] = (i < NN) ? cnt[i] : 0;
    __syncthreads();
    for (int off = 1; off < 1024; off <<= 1) {
        int t = (threadIdx.x >= (unsigned)off) ? sh[threadIdx.x - off] : 0;
        __syncthreads();
        sh[threadIdx.x] += t;
        __syncthreads();
    }
    if (i < NN) rowptr[1 + i] = sh[threadIdx.x];
    if (threadIdx.x == 1023) bsum[blockIdx.x] = sh[1023];
}

__global__ void scan_sums_kernel(int* __restrict__ bsum, int nb) {
    int lane = threadIdx.x;
    int v = (lane < nb) ? bsum[lane] : 0;
    int orig = v;
    for (int off = 1; off < 64; off <<= 1) {
        int t = __shfl_up(v, off);
        if (lane >= off) v += t;
    }
    if (lane < nb) bsum[lane] = v - orig;  // exclusive
}

__global__ void scan_add_kernel(int* __restrict__ rowptr, const int* __restrict__ bsum) {
    int i = blockIdx.x * blockDim.x + threadIdx.x;
    if (i < NN) rowptr[1 + i] += bsum[i >> 10];
    if (i == 0) rowptr[0] = 0;
}

// ---------------- fused edge MLP -> scalar aE, scattered straight into CSR
__global__ void edge_mlp_scatter_kernel(const float* __restrict__ edge_attr,
                                        const int* __restrict__ edge_index,
                                        const float* __restrict__ W1,
                                        const float* __restrict__ W2,
                                        const float* __restrict__ linW,
                                        const float* __restrict__ attE,
                                        const int* __restrict__ rowptr,
                                        int* __restrict__ wcount,
                                        int* __restrict__ csr_src,
                                        float* __restrict__ csr_aE,
                                        float* __restrict__ sumA) {
    // uniform: v[h] = linW[h]·attE ; u[g] = W2[g]·v  (scalarized by compiler)
    float v[EH];
#pragma unroll
    for (int h = 0; h < EH; h++) {
        float s = 0.f;
        for (int c = 0; c < C; c++) s += linW[h * C + c] * attE[c];
        v[h] = s;
    }
    float u[EH];
#pragma unroll
    for (int g = 0; g < EH; g++) {
        float s = 0.f;
#pragma unroll
        for (int h = 0; h < EH; h++) s += W2[g * EH + h] * v[h];
        u[g] = s;
    }
    int e = blockIdx.x * blockDim.x + threadIdx.x;
    if (e >= NE) return;
    const float* ea = edge_attr + (size_t)e * EF;
    float a = 0.f;
#pragma unroll
    for (int h = 0; h < EH; h++) {
        float s = 0.f;
#pragma unroll
        for (int f = 0; f < EF; f++) s += ea[f] * W1[f * EH + h];
        a += lrelu(s, 0.01f) * u[h];
    }
    int s = edge_index[e];
    int d = edge_index[NE + e];
    int pos = atomicAdd(&wcount[d], 1);
    int idx = rowptr[d] + pos;
    csr_src[idx] = s;
    csr_aE[idx] = a;
    atomicAdd(&sumA[d], a);
}

__global__ void aloop_kernel(const float* __restrict__ sumA, const int* __restrict__ cnt,
                             float* __restrict__ a_loop) {
    int n = blockIdx.x * blockDim.x + threadIdx.x;
    if (n < NN) a_loop[n] = sumA[n] / fmaxf((float)cnt[n], 1.0f);
}

// ---------------- h = x@W, a_s = h·att_src, a_d = h·att_dst   (one wave per (b,n))
__global__ void nodeprep_kernel(const float* __restrict__ x, const float* __restrict__ W,
                                const float* __restrict__ att_src, const float* __restrict__ att_dst,
                                float* __restrict__ h, float* __restrict__ a_s,
                                float* __restrict__ a_d) {
    __shared__ float Wl[C * C];
    for (int i = threadIdx.x; i < C * C; i += blockDim.x) Wl[i] = W[i];
    __syncthreads();
    int wid = blockIdx.x * (blockDim.x >> 6) + (threadIdx.x >> 6);
    if (wid >= NB * NN) return;
    int lane = threadIdx.x & 63;
    float xv = x[(size_t)wid * C + lane];
    float hc = 0.f;
#pragma unroll
    for (int k = 0; k < C; k++) {
        float xk = __shfl(xv, k);
        hc += xk * Wl[k * C + lane];
    }
    h[(size_t)wid * C + lane] = hc;
    float ps = hc * att_src[lane];
    float pd = hc * att_dst[lane];
    for (int off = 32; off; off >>= 1) {
        ps += __shfl_xor(ps, off);
        pd += __shfl_xor(pd, off);
    }
    if (lane == 0) {
        a_s[wid] = ps;
        a_d[wid] = pd;
    }
}

// ---------------- per-(b,n) softmax + weighted gather
// one wave per (b,n); wid = n*4 + b so a node's 4 batch-waves share a block (csr L1 reuse).
// Wave split into 4 groups x 16 lanes: 4 edges in flight, each lane a float4 of the h row.
__global__ void gather_kernel(const int* __restrict__ rowptr, const int* __restrict__ csr_src,
                              const float* __restrict__ csr_aE, const float* __restrict__ a_s,
                              const float* __restrict__ a_d, const float* __restrict__ a_loop,
                              const float* __restrict__ h, const float* __restrict__ bias,
                              float* __restrict__ out) {
    int wid = blockIdx.x * (blockDim.x >> 6) + (threadIdx.x >> 6);
    if (wid >= NB * NN) return;
    int lane = threadIdx.x & 63;
    int b = wid & (NB - 1);
    int n = wid >> 2;
    int g = lane >> 4;       // edge subgroup
    int t = lane & 15;       // float4 index within row
    int r0 = rowptr[n];
    int deg = rowptr[n + 1] - r0;
    const float* asb = a_s + (size_t)b * NN;
    float adst = a_d[(size_t)b * NN + n];
    float l_loop = lrelu(asb[n] + adst + a_loop[n], 0.2f);

    // pass 1: max over logits
    float mx = l_loop;
    for (int base = 0; base < deg; base += 64) {
        int j = base + lane;
        if (j < deg) {
            int s = csr_src[r0 + j];
            mx = fmaxf(mx, lrelu(asb[s] + adst + csr_aE[r0 + j], 0.2f));
        }
    }
#pragma unroll
    for (int off = 32; off; off >>= 1) mx = fmaxf(mx, __shfl_xor(mx, off));

    // pass 2: denom + unnormalized weighted accumulate
    const float4* hb4 = (const float4*)(h + (size_t)b * NN * C);
    float ds = 0.f;
    float4 acc = make_float4(0.f, 0.f, 0.f, 0.f);
    for (int base = 0; base < deg; base += 64) {
        int cn = min(64, deg - base);
        int j = base + lane;
        float ex = 0.f;
        int sreg = 0;
        if (j < deg) {
            sreg = csr_src[r0 + j];
            float lg = lrelu(asb[sreg] + adst + csr_aE[r0 + j], 0.2f);
            ex = __expf(lg - mx);
        }
        ds += ex;
        for (int jo = 0; jo < cn; jo += 4) {
            int j2 = jo + g;
            float al = __shfl(ex, j2);
            int sj = __shfl(sreg, j2);
            if (j2 < cn) {
                float4 hv = hb4[(size_t)sj * 16 + t];
                acc.x += al * hv.x;
                acc.y += al * hv.y;
                acc.z += al * hv.z;
                acc.w += al * hv.w;
            }
        }
    }
#pragma unroll
    for (int off = 32; off; off >>= 1) ds += __shfl_xor(ds, off);
    float eloop = __expf(l_loop - mx);
    float inv = 1.f / (ds + eloop);
    // reduce acc across the 4 groups (lanes t, t+16, t+32, t+48 hold partials)
#pragma unroll
    for (int off = 16; off < 64; off <<= 1) {
        acc.x += __shfl_xor(acc.x, off);
        acc.y += __shfl_xor(acc.y, off);
        acc.z += __shfl_xor(acc.z, off);
        acc.w += __shfl_xor(acc.w, off);
    }
    if (g == 0) {
        float4 hv = hb4[(size_t)n * 16 + t];
        float4 bv = ((const float4*)bias)[t];
        float4 o;
        o.x = (acc.x + eloop * hv.x) * inv + bv.x;
        o.y = (acc.y + eloop * hv.y) * inv + bv.y;
        o.z = (acc.z + eloop * hv.z) * inv + bv.z;
        o.w = (acc.w + eloop * hv.w) * inv + bv.w;
        o.x = o.x > 0.f ? o.x : __expf(o.x) - 1.f;
        o.y = o.y > 0.f ? o.y : __expf(o.y) - 1.f;
        o.z = o.z > 0.f ? o.z : __expf(o.z) - 1.f;
        o.w = o.w > 0.f ? o.w : __expf(o.w) - 1.f;
        ((float4*)out)[((size_t)b * NN + n) * 16 + t] = o;
    }
}

extern "C" void kernel_launch(void* const* d_in, const int* in_sizes, int n_in,
                              void* d_out, int out_size, void* d_ws, size_t ws_size,
                              hipStream_t stream) {
    const float* x      = (const float*)d_in[0];
    const int* eidx     = (const int*)d_in[1];
    const float* eattr  = (const float*)d_in[2];
    const float* W1     = (const float*)d_in[3];
    const float* W2     = (const float*)d_in[4];
    const float* W      = (const float*)d_in[5];
    const float* linW   = (const float*)d_in[6];
    const float* attS   = (const float*)d_in[7];
    const float* attD   = (const float*)d_in[8];
    const float* attE   = (const float*)d_in[9];
    const float* bias   = (const float*)d_in[10];
    float* out = (float*)d_out;

    size_t off = 0;
    auto alloc = [&](size_t bytes) {
        void* p = (char*)d_ws + off;
        off += (bytes + 255) / 256 * 256;
        return p;
    };
    float* sumA   = (float*)alloc((size_t)NN * 4);
    int* cnt      = (int*)alloc((size_t)NN * 4);
    int* wcount   = (int*)alloc((size_t)NN * 4);
    float* a_loop = (float*)alloc((size_t)NN * 4);
    int* rowptr   = (int*)alloc((size_t)(NN + 1) * 4);
    int* bsum     = (int*)alloc(64 * 4);
    int* csr_src  = (int*)alloc((size_t)NE * 4);
    float* csr_aE = (float*)alloc((size_t)NE * 4);
    float* h      = (float*)alloc((size_t)NB * NN * C * 4);
    float* a_s    = (float*)alloc((size_t)NB * NN * 4);
    float* a_d    = (float*)alloc((size_t)NB * NN * 4);
    (void)ws_size; (void)n_in; (void)in_sizes; (void)out_size;

    hipMemsetAsync(sumA, 0, (size_t)NN * 4, stream);
    hipMemsetAsync(cnt, 0, (size_t)NN * 4, stream);
    hipMemsetAsync(wcount, 0, (size_t)NN * 4, stream);

    degree_kernel<<<(NE + 255) / 256, 256, 0, stream>>>(eidx, cnt);

    int nblk = (NN + 1023) / 1024;  // 49
    scan_block_kernel<<<nblk, 1024, 0, stream>>>(cnt, rowptr, bsum);
    scan_sums_kernel<<<1, 64, 0, stream>>>(bsum, nblk);
    scan_add_kernel<<<(NN + 1023) / 1024, 1024, 0, stream>>>(rowptr, bsum);

    edge_mlp_scatter_kernel<<<(NE + 255) / 256, 256, 0, stream>>>(
        eattr, eidx, W1, W2, linW, attE, rowptr, wcount, csr_src, csr_aE, sumA);

    aloop_kernel<<<(NN + 255) / 256, 256, 0, stream>>>(sumA, cnt, a_loop);

    nodeprep_kernel<<<(NB * NN + 3) / 4, 256, 0, stream>>>(x, W, attS, attD, h, a_s, a_d);

    gather_kernel<<<(NB * NN + 3) / 4, 256, 0, stream>>>(rowptr, csr_src, csr_aE,
                                                         a_s, a_d, a_loop, h, bias, out);
}

// Round 3
// 312.030 us; speedup vs baseline: 2.0255x; 1.6247x over previous
//
#include <hip/hip_runtime.h>
#include <math.h>

#define NN 50000      // nodes
#define NE 800000     // edges
#define NB 4          // batch
#define C  64         // channels (C_IN == C_OUT)
#define EF 10
#define EH 4

__device__ __forceinline__ float lrelu(float x, float s) { return x > 0.f ? x : s * x; }

// ---------------- degree histogram
__global__ void degree_kernel(const int* __restrict__ edge_index, int* __restrict__ cnt) {
    int e = blockIdx.x * blockDim.x + threadIdx.x;
    if (e < NE) atomicAdd(&cnt[edge_index[NE + e]], 1);
}

// ---------------- two-level exclusive scan of cnt -> rowptr[N+1]
__global__ void scan_block_kernel(const int* __restrict__ cnt, int* __restrict__ rowptr,
                                  int* __restrict__ bsum) {
    __shared__ int sh[1024];
    int i = blockIdx.x * 1024 + threadIdx.x;
    sh[threadIdx.x] = (i < NN) ? cnt[i] : 0;
    __syncthreads();
    for (int off = 1; off < 1024; off <<= 1) {
        int t = (threadIdx.x >= (unsigned)off) ? sh[threadIdx.x - off] : 0;
        __syncthreads();
        sh[threadIdx.x] += t;
        __syncthreads();
    }
    if (i < NN) rowptr[1 + i] = sh[threadIdx.x];
    if (threadIdx.x == 1023) bsum[blockIdx.x] = sh[1023];
}

__global__ void scan_sums_kernel(int* __restrict__ bsum, int nb) {
    int lane = threadIdx.x;
    int v = (lane < nb) ? bsum[lane] : 0;
    int orig = v;
    for (int off = 1; off < 64; off <<= 1) {
        int t = __shfl_up(v, off);
        if (lane >= off) v += t;
    }
    if (lane < nb) bsum[lane] = v - orig;  // exclusive
}

__global__ void scan_add_kernel(int* __restrict__ rowptr, const int* __restrict__ bsum) {
    int i = blockIdx.x * blockDim.x + threadIdx.x;
    if (i < NN) rowptr[1 + i] += bsum[i >> 10];
    if (i == 0) rowptr[0] = 0;
}

// ---------------- fused edge MLP -> scalar aE, scattered straight into CSR
__global__ void edge_mlp_scatter_kernel(const float* __restrict__ edge_attr,
                                        const int* __restrict__ edge_index,
                                        const float* __restrict__ W1,
                                        const float* __restrict__ W2,
                                        const float* __restrict__ linW,
                                        const float* __restrict__ attE,
                                        const int* __restrict__ rowptr,
                                        int* __restrict__ wcount,
                                        int* __restrict__ csr_src,
                                        float* __restrict__ csr_aE,
                                        float* __restrict__ sumA) {
    float v[EH];
#pragma unroll
    for (int h = 0; h < EH; h++) {
        float s = 0.f;
        for (int c = 0; c < C; c++) s += linW[h * C + c] * attE[c];
        v[h] = s;
    }
    float u[EH];
#pragma unroll
    for (int g = 0; g < EH; g++) {
        float s = 0.f;
#pragma unroll
        for (int h = 0; h < EH; h++) s += W2[g * EH + h] * v[h];
        u[g] = s;
    }
    int e = blockIdx.x * blockDim.x + threadIdx.x;
    if (e >= NE) return;
    const float* ea = edge_attr + (size_t)e * EF;
    float a = 0.f;
#pragma unroll
    for (int h = 0; h < EH; h++) {
        float s = 0.f;
#pragma unroll
        for (int f = 0; f < EF; f++) s += ea[f] * W1[f * EH + h];
        a += lrelu(s, 0.01f) * u[h];
    }
    int s = edge_index[e];
    int d = edge_index[NE + e];
    int pos = atomicAdd(&wcount[d], 1);
    int idx = rowptr[d] + pos;
    csr_src[idx] = s;
    csr_aE[idx] = a;
    atomicAdd(&sumA[d], a);
}

__global__ void aloop_kernel(const float* __restrict__ sumA, const int* __restrict__ cnt,
                             float* __restrict__ a_loop) {
    int n = blockIdx.x * blockDim.x + threadIdx.x;
    if (n < NN) a_loop[n] = sumA[n] / fmaxf((float)cnt[n], 1.0f);
}

// ---------------- h = x@W as register-blocked tiled GEMM; fused a_s, a_d
// block = 256 threads, tile = 64 rows x 64 cols; thread computes 4 rows x 4 cols.
// per k: 2 x ds_read_b128 + 16 FMA.
__global__ void __launch_bounds__(256) nodeprep_kernel(
        const float* __restrict__ x, const float* __restrict__ W,
        const float* __restrict__ att_src, const float* __restrict__ att_dst,
        float* __restrict__ h, float* __restrict__ a_s, float* __restrict__ a_d) {
    __shared__ float Wl[C * C];   // [k][col]
    __shared__ float xT[C * 64];  // [k][row]
    int t = threadIdx.x;
    // stage W (16 KB, coalesced)
    for (int i = t * 4; i < C * C; i += 256 * 4)
        *(float4*)&Wl[i] = *(const float4*)&W[i];
    // stage x tile transposed: thread loads 64B of one row, scatters to xT[k][r]
    size_t row0 = (size_t)blockIdx.x * 64;
    int r = t >> 2;
    int k0 = (t & 3) * 16;
    const float4* xr = (const float4*)(x + (row0 + r) * C + k0);
    float4 v0 = xr[0], v1 = xr[1], v2 = xr[2], v3 = xr[3];
    xT[(k0 + 0) * 64 + r] = v0.x;  xT[(k0 + 1) * 64 + r] = v0.y;
    xT[(k0 + 2) * 64 + r] = v0.z;  xT[(k0 + 3) * 64 + r] = v0.w;
    xT[(k0 + 4) * 64 + r] = v1.x;  xT[(k0 + 5) * 64 + r] = v1.y;
    xT[(k0 + 6) * 64 + r] = v1.z;  xT[(k0 + 7) * 64 + r] = v1.w;
    xT[(k0 + 8) * 64 + r] = v2.x;  xT[(k0 + 9) * 64 + r] = v2.y;
    xT[(k0 + 10) * 64 + r] = v2.z; xT[(k0 + 11) * 64 + r] = v2.w;
    xT[(k0 + 12) * 64 + r] = v3.x; xT[(k0 + 13) * 64 + r] = v3.y;
    xT[(k0 + 14) * 64 + r] = v3.z; xT[(k0 + 15) * 64 + r] = v3.w;
    __syncthreads();

    int col4 = (t & 15) * 4;
    int row4 = (t >> 4) * 4;
    float acc[4][4];
#pragma unroll
    for (int i = 0; i < 4; i++)
#pragma unroll
        for (int j = 0; j < 4; j++) acc[i][j] = 0.f;

#pragma unroll 8
    for (int k = 0; k < C; k++) {
        float4 wv = *(float4*)&Wl[k * C + col4];
        float4 xv = *(float4*)&xT[k * 64 + row4];
        const float xs[4] = {xv.x, xv.y, xv.z, xv.w};
        const float ws[4] = {wv.x, wv.y, wv.z, wv.w};
#pragma unroll
        for (int i = 0; i < 4; i++)
#pragma unroll
            for (int j = 0; j < 4; j++) acc[i][j] += xs[i] * ws[j];
    }

    // store h (coalesced float4 rows)
#pragma unroll
    for (int i = 0; i < 4; i++) {
        float4 o = make_float4(acc[i][0], acc[i][1], acc[i][2], acc[i][3]);
        *(float4*)&h[(row0 + row4 + i) * C + col4] = o;
    }
    // fused a_s / a_d: per-thread partial over its 4 cols, reduce over 16-lane col group
    float4 sa = *(const float4*)&att_src[col4];
    float4 da = *(const float4*)&att_dst[col4];
#pragma unroll
    for (int i = 0; i < 4; i++) {
        float ps = acc[i][0] * sa.x + acc[i][1] * sa.y + acc[i][2] * sa.z + acc[i][3] * sa.w;
        float pd = acc[i][0] * da.x + acc[i][1] * da.y + acc[i][2] * da.z + acc[i][3] * da.w;
#pragma unroll
        for (int off = 8; off; off >>= 1) {
            ps += __shfl_xor(ps, off);
            pd += __shfl_xor(pd, off);
        }
        if ((t & 15) == 0) {
            a_s[row0 + row4 + i] = ps;
            a_d[row0 + row4 + i] = pd;
        }
    }
}

// ---------------- per-(b,n) softmax + weighted gather
// one wave per (b,n); wid = n*4 + b so a node's 4 batch-waves share a block (csr L1 reuse).
// Wave split into 4 groups x 16 lanes: 4 edges in flight, each lane a float4 of the h row.
__global__ void gather_kernel(const int* __restrict__ rowptr, const int* __restrict__ csr_src,
                              const float* __restrict__ csr_aE, const float* __restrict__ a_s,
                              const float* __restrict__ a_d, const float* __restrict__ a_loop,
                              const float* __restrict__ h, const float* __restrict__ bias,
                              float* __restrict__ out) {
    int wid = blockIdx.x * (blockDim.x >> 6) + (threadIdx.x >> 6);
    if (wid >= NB * NN) return;
    int lane = threadIdx.x & 63;
    int b = wid & (NB - 1);
    int n = wid >> 2;
    int g = lane >> 4;       // edge subgroup
    int t = lane & 15;       // float4 index within row
    int r0 = rowptr[n];
    int deg = rowptr[n + 1] - r0;
    const float* asb = a_s + (size_t)b * NN;
    float adst = a_d[(size_t)b * NN + n];
    float l_loop = lrelu(asb[n] + adst + a_loop[n], 0.2f);

    // pass 1: max over logits
    float mx = l_loop;
    for (int base = 0; base < deg; base += 64) {
        int j = base + lane;
        if (j < deg) {
            int s = csr_src[r0 + j];
            mx = fmaxf(mx, lrelu(asb[s] + adst + csr_aE[r0 + j], 0.2f));
        }
    }
#pragma unroll
    for (int off = 32; off; off >>= 1) mx = fmaxf(mx, __shfl_xor(mx, off));

    // pass 2: denom + unnormalized weighted accumulate
    const float4* hb4 = (const float4*)(h + (size_t)b * NN * C);
    float ds = 0.f;
    float4 acc = make_float4(0.f, 0.f, 0.f, 0.f);
    for (int base = 0; base < deg; base += 64) {
        int cn = min(64, deg - base);
        int j = base + lane;
        float ex = 0.f;
        int sreg = 0;
        if (j < deg) {
            sreg = csr_src[r0 + j];
            float lg = lrelu(asb[sreg] + adst + csr_aE[r0 + j], 0.2f);
            ex = __expf(lg - mx);
        }
        ds += ex;
        for (int jo = 0; jo < cn; jo += 4) {
            int j2 = jo + g;
            float al = __shfl(ex, j2);
            int sj = __shfl(sreg, j2);
            if (j2 < cn) {
                float4 hv = hb4[(size_t)sj * 16 + t];
                acc.x += al * hv.x;
                acc.y += al * hv.y;
                acc.z += al * hv.z;
                acc.w += al * hv.w;
            }
        }
    }
#pragma unroll
    for (int off = 32; off; off >>= 1) ds += __shfl_xor(ds, off);
    float eloop = __expf(l_loop - mx);
    float inv = 1.f / (ds + eloop);
#pragma unroll
    for (int off = 16; off < 64; off <<= 1) {
        acc.x += __shfl_xor(acc.x, off);
        acc.y += __shfl_xor(acc.y, off);
        acc.z += __shfl_xor(acc.z, off);
        acc.w += __shfl_xor(acc.w, off);
    }
    if (g == 0) {
        float4 hv = hb4[(size_t)n * 16 + t];
        float4 bv = ((const float4*)bias)[t];
        float4 o;
        o.x = (acc.x + eloop * hv.x) * inv + bv.x;
        o.y = (acc.y + eloop * hv.y) * inv + bv.y;
        o.z = (acc.z + eloop * hv.z) * inv + bv.z;
        o.w = (acc.w + eloop * hv.w) * inv + bv.w;
        o.x = o.x > 0.f ? o.x : __expf(o.x) - 1.f;
        o.y = o.y > 0.f ? o.y : __expf(o.y) - 1.f;
        o.z = o.z > 0.f ? o.z : __expf(o.z) - 1.f;
        o.w = o.w > 0.f ? o.w : __expf(o.w) - 1.f;
        ((float4*)out)[((size_t)b * NN + n) * 16 + t] = o;
    }
}

extern "C" void kernel_launch(void* const* d_in, const int* in_sizes, int n_in,
                              void* d_out, int out_size, void* d_ws, size_t ws_size,
                              hipStream_t stream) {
    const float* x      = (const float*)d_in[0];
    const int* eidx     = (const int*)d_in[1];
    const float* eattr  = (const float*)d_in[2];
    const float* W1     = (const float*)d_in[3];
    const float* W2     = (const float*)d_in[4];
    const float* W      = (const float*)d_in[5];
    const float* linW   = (const float*)d_in[6];
    const float* attS   = (const float*)d_in[7];
    const float* attD   = (const float*)d_in[8];
    const float* attE   = (const float*)d_in[9];
    const float* bias   = (const float*)d_in[10];
    float* out = (float*)d_out;

    size_t off = 0;
    auto alloc = [&](size_t bytes) {
        void* p = (char*)d_ws + off;
        off += (bytes + 255) / 256 * 256;
        return p;
    };
    float* sumA   = (float*)alloc((size_t)NN * 4);
    int* cnt      = (int*)alloc((size_t)NN * 4);
    int* wcount   = (int*)alloc((size_t)NN * 4);
    float* a_loop = (float*)alloc((size_t)NN * 4);
    int* rowptr   = (int*)alloc((size_t)(NN + 1) * 4);
    int* bsum     = (int*)alloc(64 * 4);
    int* csr_src  = (int*)alloc((size_t)NE * 4);
    float* csr_aE = (float*)alloc((size_t)NE * 4);
    float* h      = (float*)alloc((size_t)NB * NN * C * 4);
    float* a_s    = (float*)alloc((size_t)NB * NN * 4);
    float* a_d    = (float*)alloc((size_t)NB * NN * 4);
    (void)ws_size; (void)n_in; (void)in_sizes; (void)out_size;

    hipMemsetAsync(sumA, 0, (size_t)NN * 4, stream);
    hipMemsetAsync(cnt, 0, (size_t)NN * 4, stream);
    hipMemsetAsync(wcount, 0, (size_t)NN * 4, stream);

    degree_kernel<<<(NE + 255) / 256, 256, 0, stream>>>(eidx, cnt);

    int nblk = (NN + 1023) / 1024;  // 49
    scan_block_kernel<<<nblk, 1024, 0, stream>>>(cnt, rowptr, bsum);
    scan_sums_kernel<<<1, 64, 0, stream>>>(bsum, nblk);
    scan_add_kernel<<<(NN + 1023) / 1024, 1024, 0, stream>>>(rowptr, bsum);

    edge_mlp_scatter_kernel<<<(NE + 255) / 256, 256, 0, stream>>>(
        eattr, eidx, W1, W2, linW, attE, rowptr, wcount, csr_src, csr_aE, sumA);

    aloop_kernel<<<(NN + 255) / 256, 256, 0, stream>>>(sumA, cnt, a_loop);

    nodeprep_kernel<<<(NB * NN) / 64, 256, 0, stream>>>(x, W, attS, attD, h, a_s, a_d);

    gather_kernel<<<(NB * NN + 3) / 4, 256, 0, stream>>>(rowptr, csr_src, csr_aE,
                                                         a_s, a_d, a_loop, h, bias, out);
}

// Round 4
// 301.761 us; speedup vs baseline: 2.0944x; 1.0340x over previous
//
#include <hip/hip_runtime.h>
#include <math.h>

#define NN 50000      // nodes
#define NE 800000     // edges
#define NB 4          // batch
#define C  64         // channels (C_IN == C_OUT)
#define EF 10
#define EH 4

__device__ __forceinline__ float lrelu(float x, float s) { return x > 0.f ? x : s * x; }

// ---------------- degree histogram
__global__ void degree_kernel(const int* __restrict__ edge_index, int* __restrict__ cnt) {
    int e = blockIdx.x * blockDim.x + threadIdx.x;
    if (e < NE) atomicAdd(&cnt[edge_index[NE + e]], 1);
}

// ---------------- two-level exclusive scan of cnt -> rowptr[N+1]
__global__ void scan_block_kernel(const int* __restrict__ cnt, int* __restrict__ rowptr,
                                  int* __restrict__ bsum) {
    __shared__ int sh[1024];
    int i = blockIdx.x * 1024 + threadIdx.x;
    sh[threadIdx.x] = (i < NN) ? cnt[i] : 0;
    __syncthreads();
    for (int off = 1; off < 1024; off <<= 1) {
        int t = (threadIdx.x >= (unsigned)off) ? sh[threadIdx.x - off] : 0;
        __syncthreads();
        sh[threadIdx.x] += t;
        __syncthreads();
    }
    if (i < NN) rowptr[1 + i] = sh[threadIdx.x];
    if (threadIdx.x == 1023) bsum[blockIdx.x] = sh[1023];
}

__global__ void scan_sums_kernel(int* __restrict__ bsum, int nb) {
    int lane = threadIdx.x;
    int v = (lane < nb) ? bsum[lane] : 0;
    int orig = v;
    for (int off = 1; off < 64; off <<= 1) {
        int t = __shfl_up(v, off);
        if (lane >= off) v += t;
    }
    if (lane < nb) bsum[lane] = v - orig;  // exclusive
}

__global__ void scan_add_kernel(int* __restrict__ rowptr, const int* __restrict__ bsum) {
    int i = blockIdx.x * blockDim.x + threadIdx.x;
    if (i < NN) rowptr[1 + i] += bsum[i >> 10];
    if (i == 0) rowptr[0] = 0;
}

// ---------------- fused edge MLP -> scalar aE, scattered straight into CSR
__global__ void edge_mlp_scatter_kernel(const float* __restrict__ edge_attr,
                                        const int* __restrict__ edge_index,
                                        const float* __restrict__ W1,
                                        const float* __restrict__ W2,
                                        const float* __restrict__ linW,
                                        const float* __restrict__ attE,
                                        const int* __restrict__ rowptr,
                                        int* __restrict__ wcount,
                                        int* __restrict__ csr_src,
                                        float* __restrict__ csr_aE,
                                        float* __restrict__ sumA) {
    float v[EH];
#pragma unroll
    for (int h = 0; h < EH; h++) {
        float s = 0.f;
        for (int c = 0; c < C; c++) s += linW[h * C + c] * attE[c];
        v[h] = s;
    }
    float u[EH];
#pragma unroll
    for (int g = 0; g < EH; g++) {
        float s = 0.f;
#pragma unroll
        for (int h = 0; h < EH; h++) s += W2[g * EH + h] * v[h];
        u[g] = s;
    }
    int e = blockIdx.x * blockDim.x + threadIdx.x;
    if (e >= NE) return;
    const float* ea = edge_attr + (size_t)e * EF;
    float a = 0.f;
#pragma unroll
    for (int h = 0; h < EH; h++) {
        float s = 0.f;
#pragma unroll
        for (int f = 0; f < EF; f++) s += ea[f] * W1[f * EH + h];
        a += lrelu(s, 0.01f) * u[h];
    }
    int s = edge_index[e];
    int d = edge_index[NE + e];
    int pos = atomicAdd(&wcount[d], 1);
    int idx = rowptr[d] + pos;
    csr_src[idx] = s;
    csr_aE[idx] = a;
    atomicAdd(&sumA[d], a);
}

__global__ void aloop_kernel(const float* __restrict__ sumA, const int* __restrict__ cnt,
                             float* __restrict__ a_loop) {
    int n = blockIdx.x * blockDim.x + threadIdx.x;
    if (n < NN) a_loop[n] = sumA[n] / fmaxf((float)cnt[n], 1.0f);
}

// ---------------- h = x@W as register-blocked tiled GEMM; fused a_s, a_d
__global__ void __launch_bounds__(256) nodeprep_kernel(
        const float* __restrict__ x, const float* __restrict__ W,
        const float* __restrict__ att_src, const float* __restrict__ att_dst,
        float* __restrict__ h, float* __restrict__ a_s, float* __restrict__ a_d) {
    __shared__ float Wl[C * C];   // [k][col]
    __shared__ float xT[C * 64];  // [k][row]
    int t = threadIdx.x;
    for (int i = t * 4; i < C * C; i += 256 * 4)
        *(float4*)&Wl[i] = *(const float4*)&W[i];
    size_t row0 = (size_t)blockIdx.x * 64;
    int r = t >> 2;
    int k0 = (t & 3) * 16;
    const float4* xr = (const float4*)(x + (row0 + r) * C + k0);
    float4 v0 = xr[0], v1 = xr[1], v2 = xr[2], v3 = xr[3];
    xT[(k0 + 0) * 64 + r] = v0.x;  xT[(k0 + 1) * 64 + r] = v0.y;
    xT[(k0 + 2) * 64 + r] = v0.z;  xT[(k0 + 3) * 64 + r] = v0.w;
    xT[(k0 + 4) * 64 + r] = v1.x;  xT[(k0 + 5) * 64 + r] = v1.y;
    xT[(k0 + 6) * 64 + r] = v1.z;  xT[(k0 + 7) * 64 + r] = v1.w;
    xT[(k0 + 8) * 64 + r] = v2.x;  xT[(k0 + 9) * 64 + r] = v2.y;
    xT[(k0 + 10) * 64 + r] = v2.z; xT[(k0 + 11) * 64 + r] = v2.w;
    xT[(k0 + 12) * 64 + r] = v3.x; xT[(k0 + 13) * 64 + r] = v3.y;
    xT[(k0 + 14) * 64 + r] = v3.z; xT[(k0 + 15) * 64 + r] = v3.w;
    __syncthreads();

    int col4 = (t & 15) * 4;
    int row4 = (t >> 4) * 4;
    float acc[4][4];
#pragma unroll
    for (int i = 0; i < 4; i++)
#pragma unroll
        for (int j = 0; j < 4; j++) acc[i][j] = 0.f;

#pragma unroll 8
    for (int k = 0; k < C; k++) {
        float4 wv = *(float4*)&Wl[k * C + col4];
        float4 xv = *(float4*)&xT[k * 64 + row4];
        const float xs[4] = {xv.x, xv.y, xv.z, xv.w};
        const float ws[4] = {wv.x, wv.y, wv.z, wv.w};
#pragma unroll
        for (int i = 0; i < 4; i++)
#pragma unroll
            for (int j = 0; j < 4; j++) acc[i][j] += xs[i] * ws[j];
    }

#pragma unroll
    for (int i = 0; i < 4; i++) {
        float4 o = make_float4(acc[i][0], acc[i][1], acc[i][2], acc[i][3]);
        *(float4*)&h[(row0 + row4 + i) * C + col4] = o;
    }
    float4 sa = *(const float4*)&att_src[col4];
    float4 da = *(const float4*)&att_dst[col4];
#pragma unroll
    for (int i = 0; i < 4; i++) {
        float ps = acc[i][0] * sa.x + acc[i][1] * sa.y + acc[i][2] * sa.z + acc[i][3] * sa.w;
        float pd = acc[i][0] * da.x + acc[i][1] * da.y + acc[i][2] * da.z + acc[i][3] * da.w;
#pragma unroll
        for (int off = 8; off; off >>= 1) {
            ps += __shfl_xor(ps, off);
            pd += __shfl_xor(pd, off);
        }
        if ((t & 15) == 0) {
            a_s[row0 + row4 + i] = ps;
            a_d[row0 + row4 + i] = pd;
        }
    }
}

// ---------------- softmax + weighted gather: ONE WAVE PER NODE, group g = batch b.
// All 4 groups share identical csr loads (L1 broadcast) and have identical deg ->
// zero inter-group divergence. Single sweep: no max pass (logits bounded ~12,
// exp is fp32-safe), unnormalized accumulate, divide at end. Lane t owns cols
// 4t..4t+3 of its batch's output row -> no cross-lane accumulator reduce.
__global__ void gather_kernel(const int* __restrict__ rowptr, const int* __restrict__ csr_src,
                              const float* __restrict__ csr_aE, const float* __restrict__ a_s,
                              const float* __restrict__ a_d, const float* __restrict__ a_loop,
                              const float* __restrict__ h, const float* __restrict__ bias,
                              float* __restrict__ out) {
    int n = blockIdx.x * (blockDim.x >> 6) + (threadIdx.x >> 6);
    if (n >= NN) return;
    int lane = threadIdx.x & 63;
    int b = lane >> 4;       // group = batch
    int t = lane & 15;       // float4 index within output row
    int r0 = rowptr[n];
    int deg = rowptr[n + 1] - r0;
    const float* asb = a_s + (size_t)b * NN;
    float adst = a_d[(size_t)b * NN + n];
    float eloop = __expf(lrelu(asb[n] + adst + a_loop[n], 0.2f));

    const float4* hb4 = (const float4*)(h + (size_t)b * NN * C);
    float ds = 0.f;
    float4 acc = make_float4(0.f, 0.f, 0.f, 0.f);
    for (int base = 0; base < deg; base += 16) {
        int j = base + t;
        float ex = 0.f;
        int sreg = 0;
        if (j < deg) {
            sreg = csr_src[r0 + j];
            ex = __expf(lrelu(asb[sreg] + adst + csr_aE[r0 + j], 0.2f));
        }
        ds += ex;
        int cn = min(16, deg - base);
#pragma unroll 4
        for (int jj = 0; jj < cn; jj++) {
            int sl = (b << 4) + jj;
            float al = __shfl(ex, sl);
            int sj = __shfl(sreg, sl);
            float4 hv = hb4[(size_t)sj * 16 + t];
            acc.x += al * hv.x;
            acc.y += al * hv.y;
            acc.z += al * hv.z;
            acc.w += al * hv.w;
        }
    }
    // denom reduce within the 16-lane group
#pragma unroll
    for (int off = 8; off; off >>= 1) ds += __shfl_xor(ds, off);
    float inv = 1.f / (ds + eloop);
    float4 hv = hb4[(size_t)n * 16 + t];
    float4 bv = ((const float4*)bias)[t];
    float4 o;
    o.x = (acc.x + eloop * hv.x) * inv + bv.x;
    o.y = (acc.y + eloop * hv.y) * inv + bv.y;
    o.z = (acc.z + eloop * hv.z) * inv + bv.z;
    o.w = (acc.w + eloop * hv.w) * inv + bv.w;
    o.x = o.x > 0.f ? o.x : __expf(o.x) - 1.f;
    o.y = o.y > 0.f ? o.y : __expf(o.y) - 1.f;
    o.z = o.z > 0.f ? o.z : __expf(o.z) - 1.f;
    o.w = o.w > 0.f ? o.w : __expf(o.w) - 1.f;
    ((float4*)out)[((size_t)b * NN + n) * 16 + t] = o;
}

extern "C" void kernel_launch(void* const* d_in, const int* in_sizes, int n_in,
                              void* d_out, int out_size, void* d_ws, size_t ws_size,
                              hipStream_t stream) {
    const float* x      = (const float*)d_in[0];
    const int* eidx     = (const int*)d_in[1];
    const float* eattr  = (const float*)d_in[2];
    const float* W1     = (const float*)d_in[3];
    const float* W2     = (const float*)d_in[4];
    const float* W      = (const float*)d_in[5];
    const float* linW   = (const float*)d_in[6];
    const float* attS   = (const float*)d_in[7];
    const float* attD   = (const float*)d_in[8];
    const float* attE   = (const float*)d_in[9];
    const float* bias   = (const float*)d_in[10];
    float* out = (float*)d_out;

    size_t off = 0;
    auto alloc = [&](size_t bytes) {
        void* p = (char*)d_ws + off;
        off += (bytes + 255) / 256 * 256;
        return p;
    };
    float* sumA   = (float*)alloc((size_t)NN * 4);
    int* cnt      = (int*)alloc((size_t)NN * 4);
    int* wcount   = (int*)alloc((size_t)NN * 4);
    float* a_loop = (float*)alloc((size_t)NN * 4);
    int* rowptr   = (int*)alloc((size_t)(NN + 1) * 4);
    int* bsum     = (int*)alloc(64 * 4);
    int* csr_src  = (int*)alloc((size_t)NE * 4);
    float* csr_aE = (float*)alloc((size_t)NE * 4);
    float* h      = (float*)alloc((size_t)NB * NN * C * 4);
    float* a_s    = (float*)alloc((size_t)NB * NN * 4);
    float* a_d    = (float*)alloc((size_t)NB * NN * 4);
    (void)ws_size; (void)n_in; (void)in_sizes; (void)out_size;

    hipMemsetAsync(sumA, 0, (size_t)NN * 4, stream);
    hipMemsetAsync(cnt, 0, (size_t)NN * 4, stream);
    hipMemsetAsync(wcount, 0, (size_t)NN * 4, stream);

    degree_kernel<<<(NE + 255) / 256, 256, 0, stream>>>(eidx, cnt);

    int nblk = (NN + 1023) / 1024;  // 49
    scan_block_kernel<<<nblk, 1024, 0, stream>>>(cnt, rowptr, bsum);
    scan_sums_kernel<<<1, 64, 0, stream>>>(bsum, nblk);
    scan_add_kernel<<<(NN + 1023) / 1024, 1024, 0, stream>>>(rowptr, bsum);

    edge_mlp_scatter_kernel<<<(NE + 255) / 256, 256, 0, stream>>>(
        eattr, eidx, W1, W2, linW, attE, rowptr, wcount, csr_src, csr_aE, sumA);

    aloop_kernel<<<(NN + 255) / 256, 256, 0, stream>>>(sumA, cnt, a_loop);

    nodeprep_kernel<<<(NB * NN) / 64, 256, 0, stream>>>(x, W, attS, attD, h, a_s, a_d);

    gather_kernel<<<(NN + 3) / 4, 256, 0, stream>>>(rowptr, csr_src, csr_aE,
                                                    a_s, a_d, a_loop, h, bias, out);
}

// Round 5
// 250.418 us; speedup vs baseline: 2.5238x; 1.2050x over previous
//
#include <hip/hip_runtime.h>
#include <math.h>

#define NN 50000      // nodes
#define NE 800000     // edges
#define NB 4          // batch
#define C  64         // channels (C_IN == C_OUT)
#define EF 10
#define EH 4

__device__ __forceinline__ float lrelu(float x, float s) { return x > 0.f ? x : s * x; }

__device__ __forceinline__ unsigned int f2bf(float f) {  // RNE bf16, returned in low 16
    unsigned u = __float_as_uint(f);
    u += 0x7FFF + ((u >> 16) & 1);
    return u >> 16;
}

// ---------------- degree histogram
__global__ void degree_kernel(const int* __restrict__ edge_index, int* __restrict__ cnt) {
    int e = blockIdx.x * blockDim.x + threadIdx.x;
    if (e < NE) atomicAdd(&cnt[edge_index[NE + e]], 1);
}

// ---------------- two-level exclusive scan of cnt -> rowptr[N+1]
__global__ void scan_block_kernel(const int* __restrict__ cnt, int* __restrict__ rowptr,
                                  int* __restrict__ bsum) {
    __shared__ int sh[1024];
    int i = blockIdx.x * 1024 + threadIdx.x;
    sh[threadIdx.x] = (i < NN) ? cnt[i] : 0;
    __syncthreads();
    for (int off = 1; off < 1024; off <<= 1) {
        int t = (threadIdx.x >= (unsigned)off) ? sh[threadIdx.x - off] : 0;
        __syncthreads();
        sh[threadIdx.x] += t;
        __syncthreads();
    }
    if (i < NN) rowptr[1 + i] = sh[threadIdx.x];
    if (threadIdx.x == 1023) bsum[blockIdx.x] = sh[1023];
}

__global__ void scan_sums_kernel(int* __restrict__ bsum, int nb) {
    int lane = threadIdx.x;
    int v = (lane < nb) ? bsum[lane] : 0;
    int orig = v;
    for (int off = 1; off < 64; off <<= 1) {
        int t = __shfl_up(v, off);
        if (lane >= off) v += t;
    }
    if (lane < nb) bsum[lane] = v - orig;  // exclusive
}

__global__ void scan_add_kernel(int* __restrict__ rowptr, const int* __restrict__ bsum) {
    int i = blockIdx.x * blockDim.x + threadIdx.x;
    if (i < NN) rowptr[1 + i] += bsum[i >> 10];
    if (i == 0) rowptr[0] = 0;
}

// ---------------- fused edge MLP -> scalar aE, scattered into packed CSR (src, aE)
__global__ void edge_mlp_scatter_kernel(const float* __restrict__ edge_attr,
                                        const int* __restrict__ edge_index,
                                        const float* __restrict__ W1,
                                        const float* __restrict__ W2,
                                        const float* __restrict__ linW,
                                        const float* __restrict__ attE,
                                        const int* __restrict__ rowptr,
                                        int* __restrict__ wcount,
                                        uint2* __restrict__ csr,
                                        float* __restrict__ sumA) {
    float v[EH];
#pragma unroll
    for (int h = 0; h < EH; h++) {
        float s = 0.f;
        for (int c = 0; c < C; c++) s += linW[h * C + c] * attE[c];
        v[h] = s;
    }
    float u[EH];
#pragma unroll
    for (int g = 0; g < EH; g++) {
        float s = 0.f;
#pragma unroll
        for (int h = 0; h < EH; h++) s += W2[g * EH + h] * v[h];
        u[g] = s;
    }
    int e = blockIdx.x * blockDim.x + threadIdx.x;
    if (e >= NE) return;
    const float* ea = edge_attr + (size_t)e * EF;
    float a = 0.f;
#pragma unroll
    for (int h = 0; h < EH; h++) {
        float s = 0.f;
#pragma unroll
        for (int f = 0; f < EF; f++) s += ea[f] * W1[f * EH + h];
        a += lrelu(s, 0.01f) * u[h];
    }
    int s = edge_index[e];
    int d = edge_index[NE + e];
    int pos = atomicAdd(&wcount[d], 1);
    uint2 p;
    p.x = (unsigned)s;
    p.y = __float_as_uint(a);
    csr[rowptr[d] + pos] = p;
    atomicAdd(&sumA[d], a);
}

__global__ void aloop_kernel(const float* __restrict__ sumA, const int* __restrict__ cnt,
                             float* __restrict__ a_loop) {
    int n = blockIdx.x * blockDim.x + threadIdx.x;
    if (n < NN) a_loop[n] = sumA[n] / fmaxf((float)cnt[n], 1.0f);
}

// ---------------- h = x@W tiled GEMM; h stored bf16 interleaved [n][b][c]; fused a_s,a_d
__global__ void __launch_bounds__(256) nodeprep_kernel(
        const float* __restrict__ x, const float* __restrict__ W,
        const float* __restrict__ att_src, const float* __restrict__ att_dst,
        unsigned* __restrict__ hbf,  // [NN][NB][C] bf16 as uint pairs: NN*NB*C/2 uints
        float* __restrict__ a_s, float* __restrict__ a_d) {
    __shared__ float Wl[C * C];   // [k][col]
    __shared__ float xT[C * 64];  // [k][row]
    int t = threadIdx.x;
    for (int i = t * 4; i < C * C; i += 256 * 4)
        *(float4*)&Wl[i] = *(const float4*)&W[i];
    size_t row0 = (size_t)blockIdx.x * 64;
    int r = t >> 2;
    int k0 = (t & 3) * 16;
    const float4* xr = (const float4*)(x + (row0 + r) * C + k0);
    float4 v0 = xr[0], v1 = xr[1], v2 = xr[2], v3 = xr[3];
    xT[(k0 + 0) * 64 + r] = v0.x;  xT[(k0 + 1) * 64 + r] = v0.y;
    xT[(k0 + 2) * 64 + r] = v0.z;  xT[(k0 + 3) * 64 + r] = v0.w;
    xT[(k0 + 4) * 64 + r] = v1.x;  xT[(k0 + 5) * 64 + r] = v1.y;
    xT[(k0 + 6) * 64 + r] = v1.z;  xT[(k0 + 7) * 64 + r] = v1.w;
    xT[(k0 + 8) * 64 + r] = v2.x;  xT[(k0 + 9) * 64 + r] = v2.y;
    xT[(k0 + 10) * 64 + r] = v2.z; xT[(k0 + 11) * 64 + r] = v2.w;
    xT[(k0 + 12) * 64 + r] = v3.x; xT[(k0 + 13) * 64 + r] = v3.y;
    xT[(k0 + 14) * 64 + r] = v3.z; xT[(k0 + 15) * 64 + r] = v3.w;
    __syncthreads();

    int col4 = (t & 15) * 4;
    int row4 = (t >> 4) * 4;
    float acc[4][4];
#pragma unroll
    for (int i = 0; i < 4; i++)
#pragma unroll
        for (int j = 0; j < 4; j++) acc[i][j] = 0.f;

#pragma unroll 8
    for (int k = 0; k < C; k++) {
        float4 wv = *(float4*)&Wl[k * C + col4];
        float4 xv = *(float4*)&xT[k * 64 + row4];
        const float xs[4] = {xv.x, xv.y, xv.z, xv.w};
        const float ws[4] = {wv.x, wv.y, wv.z, wv.w};
#pragma unroll
        for (int i = 0; i < 4; i++)
#pragma unroll
            for (int j = 0; j < 4; j++) acc[i][j] += xs[i] * ws[j];
    }

    // store h as bf16 at [n][b][col]: row gr = b*NN + n
#pragma unroll
    for (int i = 0; i < 4; i++) {
        size_t gr = row0 + row4 + i;
        int b = (int)(gr / NN);
        int n = (int)(gr - (size_t)b * NN);
        uint2 p;
        p.x = f2bf(acc[i][0]) | (f2bf(acc[i][1]) << 16);
        p.y = f2bf(acc[i][2]) | (f2bf(acc[i][3]) << 16);
        // uint index: ((n*NB + b)*C + col4) / 2
        *(uint2*)&hbf[((size_t)n * NB + b) * (C / 2) + (col4 >> 1)] = p;
    }
    float4 sa = *(const float4*)&att_src[col4];
    float4 da = *(const float4*)&att_dst[col4];
#pragma unroll
    for (int i = 0; i < 4; i++) {
        float ps = acc[i][0] * sa.x + acc[i][1] * sa.y + acc[i][2] * sa.z + acc[i][3] * sa.w;
        float pd = acc[i][0] * da.x + acc[i][1] * da.y + acc[i][2] * da.z + acc[i][3] * da.w;
#pragma unroll
        for (int off = 8; off; off >>= 1) {
            ps += __shfl_xor(ps, off);
            pd += __shfl_xor(pd, off);
        }
        if ((t & 15) == 0) {
            a_s[row0 + row4 + i] = ps;
            a_d[row0 + row4 + i] = pd;
        }
    }
}

// ---------------- softmax + weighted gather: one wave per node, group = batch.
// h is bf16 interleaved [n][b][c] -> per edge the wave reads one contiguous 512 B block.
__global__ void gather_kernel(const int* __restrict__ rowptr, const uint2* __restrict__ csr,
                              const float* __restrict__ a_s, const float* __restrict__ a_d,
                              const float* __restrict__ a_loop,
                              const uint2* __restrict__ hbf,  // [n][b][c] bf16, uint2 = 4 ch
                              const float* __restrict__ bias, float* __restrict__ out) {
    int n = blockIdx.x * (blockDim.x >> 6) + (threadIdx.x >> 6);
    if (n >= NN) return;
    int lane = threadIdx.x & 63;
    int b = lane >> 4;       // group = batch
    int t = lane & 15;       // float4 (4-channel) index within row
    int r0 = rowptr[n];
    int deg = rowptr[n + 1] - r0;
    const float* asb = a_s + (size_t)b * NN;
    float adst = a_d[(size_t)b * NN + n];
    float eloop = __expf(lrelu(asb[n] + adst + a_loop[n], 0.2f));

    // uint2 index for (node s, batch b, chans 4t..4t+3): s*(NB*C/4) + b*(C/4) + t
    float ds = 0.f;
    float4 acc = make_float4(0.f, 0.f, 0.f, 0.f);
    for (int base = 0; base < deg; base += 16) {
        int j = base + t;
        float ex = 0.f;
        int sreg = 0;
        if (j < deg) {
            uint2 pr = csr[r0 + j];
            sreg = (int)pr.x;
            ex = __expf(lrelu(asb[sreg] + adst + __uint_as_float(pr.y), 0.2f));
        }
        ds += ex;
        int cn = min(16, deg - base);
#pragma unroll 4
        for (int jj = 0; jj < cn; jj++) {
            int sl = (b << 4) + jj;
            float al = __shfl(ex, sl);
            int sj = __shfl(sreg, sl);
            uint2 hv = hbf[(size_t)sj * (NB * C / 4) + (b << 4) + t];
            acc.x += al * __uint_as_float(hv.x << 16);
            acc.y += al * __uint_as_float(hv.x & 0xFFFF0000u);
            acc.z += al * __uint_as_float(hv.y << 16);
            acc.w += al * __uint_as_float(hv.y & 0xFFFF0000u);
        }
    }
#pragma unroll
    for (int off = 8; off; off >>= 1) ds += __shfl_xor(ds, off);
    float inv = 1.f / (ds + eloop);
    uint2 hv = hbf[(size_t)n * (NB * C / 4) + (b << 4) + t];
    float4 bv = ((const float4*)bias)[t];
    float4 o;
    o.x = (acc.x + eloop * __uint_as_float(hv.x << 16)) * inv + bv.x;
    o.y = (acc.y + eloop * __uint_as_float(hv.x & 0xFFFF0000u)) * inv + bv.y;
    o.z = (acc.z + eloop * __uint_as_float(hv.y << 16)) * inv + bv.z;
    o.w = (acc.w + eloop * __uint_as_float(hv.y & 0xFFFF0000u)) * inv + bv.w;
    o.x = o.x > 0.f ? o.x : __expf(o.x) - 1.f;
    o.y = o.y > 0.f ? o.y : __expf(o.y) - 1.f;
    o.z = o.z > 0.f ? o.z : __expf(o.z) - 1.f;
    o.w = o.w > 0.f ? o.w : __expf(o.w) - 1.f;
    ((float4*)out)[((size_t)b * NN + n) * 16 + t] = o;
}

extern "C" void kernel_launch(void* const* d_in, const int* in_sizes, int n_in,
                              void* d_out, int out_size, void* d_ws, size_t ws_size,
                              hipStream_t stream) {
    const float* x      = (const float*)d_in[0];
    const int* eidx     = (const int*)d_in[1];
    const float* eattr  = (const float*)d_in[2];
    const float* W1     = (const float*)d_in[3];
    const float* W2     = (const float*)d_in[4];
    const float* W      = (const float*)d_in[5];
    const float* linW   = (const float*)d_in[6];
    const float* attS   = (const float*)d_in[7];
    const float* attD   = (const float*)d_in[8];
    const float* attE   = (const float*)d_in[9];
    const float* bias   = (const float*)d_in[10];
    float* out = (float*)d_out;

    size_t off = 0;
    auto alloc = [&](size_t bytes) {
        void* p = (char*)d_ws + off;
        off += (bytes + 255) / 256 * 256;
        return p;
    };
    float* sumA   = (float*)alloc((size_t)NN * 4);
    int* cnt      = (int*)alloc((size_t)NN * 4);
    int* wcount   = (int*)alloc((size_t)NN * 4);
    float* a_loop = (float*)alloc((size_t)NN * 4);
    int* rowptr   = (int*)alloc((size_t)(NN + 1) * 4);
    int* bsum     = (int*)alloc(64 * 4);
    uint2* csr    = (uint2*)alloc((size_t)NE * 8);
    unsigned* hbf = (unsigned*)alloc((size_t)NN * NB * C * 2);  // bf16
    float* a_s    = (float*)alloc((size_t)NB * NN * 4);
    float* a_d    = (float*)alloc((size_t)NB * NN * 4);
    (void)ws_size; (void)n_in; (void)in_sizes; (void)out_size;

    hipMemsetAsync(sumA, 0, (size_t)NN * 4, stream);
    hipMemsetAsync(cnt, 0, (size_t)NN * 4, stream);
    hipMemsetAsync(wcount, 0, (size_t)NN * 4, stream);

    degree_kernel<<<(NE + 255) / 256, 256, 0, stream>>>(eidx, cnt);

    int nblk = (NN + 1023) / 1024;  // 49
    scan_block_kernel<<<nblk, 1024, 0, stream>>>(cnt, rowptr, bsum);
    scan_sums_kernel<<<1, 64, 0, stream>>>(bsum, nblk);
    scan_add_kernel<<<(NN + 1023) / 1024, 1024, 0, stream>>>(rowptr, bsum);

    edge_mlp_scatter_kernel<<<(NE + 255) / 256, 256, 0, stream>>>(
        eattr, eidx, W1, W2, linW, attE, rowptr, wcount, csr, sumA);

    aloop_kernel<<<(NN + 255) / 256, 256, 0, stream>>>(sumA, cnt, a_loop);

    nodeprep_kernel<<<(NB * NN) / 64, 256, 0, stream>>>(x, W, attS, attD, hbf, a_s, a_d);

    gather_kernel<<<(NN + 3) / 4, 256, 0, stream>>>(rowptr, csr, a_s, a_d, a_loop,
                                                    (const uint2*)hbf, bias, out);
}

// Round 7
// 215.919 us; speedup vs baseline: 2.9270x; 1.1598x over previous
//
#include <hip/hip_runtime.h>
#include <math.h>

#define NN 50000      // nodes
#define NE 800000     // edges
#define NB 4          // batch
#define C  64         // channels (C_IN == C_OUT)
#define EF 10
#define EH 4

__device__ __forceinline__ float lrelu(float x, float s) { return x > 0.f ? x : s * x; }

__device__ __forceinline__ unsigned int f2bf(float f) {  // RNE bf16, returned in low 16
    unsigned u = __float_as_uint(f);
    u += 0x7FFF + ((u >> 16) & 1);
    return u >> 16;
}

// ---------------- degree histogram
__global__ void degree_kernel(const int* __restrict__ edge_index, int* __restrict__ cnt) {
    int e = blockIdx.x * blockDim.x + threadIdx.x;
    if (e < NE) atomicAdd(&cnt[edge_index[NE + e]], 1);
}

// ---------------- two-level exclusive scan of cnt -> rowptr[N+1]
__global__ void scan_block_kernel(const int* __restrict__ cnt, int* __restrict__ rowptr,
                                  int* __restrict__ bsum) {
    __shared__ int sh[1024];
    int i = blockIdx.x * 1024 + threadIdx.x;
    sh[threadIdx.x] = (i < NN) ? cnt[i] : 0;
    __syncthreads();
    for (int off = 1; off < 1024; off <<= 1) {
        int t = (threadIdx.x >= (unsigned)off) ? sh[threadIdx.x - off] : 0;
        __syncthreads();
        sh[threadIdx.x] += t;
        __syncthreads();
    }
    if (i < NN) rowptr[1 + i] = sh[threadIdx.x];
    if (threadIdx.x == 1023) bsum[blockIdx.x] = sh[1023];
}

__global__ void scan_sums_kernel(int* __restrict__ bsum, int nb) {
    int lane = threadIdx.x;
    int v = (lane < nb) ? bsum[lane] : 0;
    int orig = v;
    for (int off = 1; off < 64; off <<= 1) {
        int t = __shfl_up(v, off);
        if (lane >= off) v += t;
    }
    if (lane < nb) bsum[lane] = v - orig;  // exclusive
}

__global__ void scan_add_kernel(int* __restrict__ rowptr, const int* __restrict__ bsum) {
    int i = blockIdx.x * blockDim.x + threadIdx.x;
    if (i < NN) rowptr[1 + i] += bsum[i >> 10];
    if (i == 0) rowptr[0] = 0;
}

// ---------------- fused edge MLP -> scalar aE, scattered into packed CSR (src, aE)
// wcount is pre-seeded with rowptr, so the atomic returns the final csr index.
// 2 edges per thread (stride NE/2) for independent latency chains.
__global__ void edge_mlp_scatter_kernel(const float* __restrict__ edge_attr,
                                        const int* __restrict__ edge_index,
                                        const float* __restrict__ W1,
                                        const float* __restrict__ W2,
                                        const float* __restrict__ linW,
                                        const float* __restrict__ attE,
                                        int* __restrict__ wcount,
                                        uint2* __restrict__ csr) {
    float v[EH];
#pragma unroll
    for (int h = 0; h < EH; h++) {
        float s = 0.f;
        for (int c = 0; c < C; c++) s += linW[h * C + c] * attE[c];
        v[h] = s;
    }
    float u[EH];
#pragma unroll
    for (int g = 0; g < EH; g++) {
        float s = 0.f;
#pragma unroll
        for (int h = 0; h < EH; h++) s += W2[g * EH + h] * v[h];
        u[g] = s;
    }
    int g0 = blockIdx.x * blockDim.x + threadIdx.x;
    if (g0 >= NE / 2) return;   // each thread owns exactly edges g0 and g0+NE/2
#pragma unroll
    for (int q = 0; q < 2; q++) {
        int e = g0 + q * (NE / 2);
        const float* ea = edge_attr + (size_t)e * EF;
        float a = 0.f;
#pragma unroll
        for (int h = 0; h < EH; h++) {
            float s = 0.f;
#pragma unroll
            for (int f = 0; f < EF; f++) s += ea[f] * W1[f * EH + h];
            a += lrelu(s, 0.01f) * u[h];
        }
        int s = edge_index[e];
        int d = edge_index[NE + e];
        int idx = atomicAdd(&wcount[d], 1);
        uint2 p;
        p.x = (unsigned)s;
        p.y = __float_as_uint(a);
        csr[idx] = p;
    }
}

// ---------------- h = x@W tiled GEMM; h stored bf16 interleaved [n][b][c]; fused a_s,a_d
__global__ void __launch_bounds__(256) nodeprep_kernel(
        const float* __restrict__ x, const float* __restrict__ W,
        const float* __restrict__ att_src, const float* __restrict__ att_dst,
        unsigned* __restrict__ hbf,  // [NN][NB][C] bf16
        float* __restrict__ a_s, float* __restrict__ a_d) {
    __shared__ float Wl[C * C];   // [k][col]
    __shared__ float xT[C * 64];  // [k][row]
    int t = threadIdx.x;
    for (int i = t * 4; i < C * C; i += 256 * 4)
        *(float4*)&Wl[i] = *(const float4*)&W[i];
    size_t row0 = (size_t)blockIdx.x * 64;
    int r = t >> 2;
    int k0 = (t & 3) * 16;
    const float4* xr = (const float4*)(x + (row0 + r) * C + k0);
    float4 v0 = xr[0], v1 = xr[1], v2 = xr[2], v3 = xr[3];
    xT[(k0 + 0) * 64 + r] = v0.x;  xT[(k0 + 1) * 64 + r] = v0.y;
    xT[(k0 + 2) * 64 + r] = v0.z;  xT[(k0 + 3) * 64 + r] = v0.w;
    xT[(k0 + 4) * 64 + r] = v1.x;  xT[(k0 + 5) * 64 + r] = v1.y;
    xT[(k0 + 6) * 64 + r] = v1.z;  xT[(k0 + 7) * 64 + r] = v1.w;
    xT[(k0 + 8) * 64 + r] = v2.x;  xT[(k0 + 9) * 64 + r] = v2.y;
    xT[(k0 + 10) * 64 + r] = v2.z; xT[(k0 + 11) * 64 + r] = v2.w;
    xT[(k0 + 12) * 64 + r] = v3.x; xT[(k0 + 13) * 64 + r] = v3.y;
    xT[(k0 + 14) * 64 + r] = v3.z; xT[(k0 + 15) * 64 + r] = v3.w;
    __syncthreads();

    int col4 = (t & 15) * 4;
    int row4 = (t >> 4) * 4;
    float acc[4][4];
#pragma unroll
    for (int i = 0; i < 4; i++)
#pragma unroll
        for (int j = 0; j < 4; j++) acc[i][j] = 0.f;

#pragma unroll 8
    for (int k = 0; k < C; k++) {
        float4 wv = *(float4*)&Wl[k * C + col4];
        float4 xv = *(float4*)&xT[k * 64 + row4];
        const float xs[4] = {xv.x, xv.y, xv.z, xv.w};
        const float ws[4] = {wv.x, wv.y, wv.z, wv.w};
#pragma unroll
        for (int i = 0; i < 4; i++)
#pragma unroll
            for (int j = 0; j < 4; j++) acc[i][j] += xs[i] * ws[j];
    }

#pragma unroll
    for (int i = 0; i < 4; i++) {
        size_t gr = row0 + row4 + i;
        int b = (int)(gr / NN);
        int n = (int)(gr - (size_t)b * NN);
        uint2 p;
        p.x = f2bf(acc[i][0]) | (f2bf(acc[i][1]) << 16);
        p.y = f2bf(acc[i][2]) | (f2bf(acc[i][3]) << 16);
        *(uint2*)&hbf[((size_t)n * NB + b) * (C / 2) + (col4 >> 1)] = p;
    }
    float4 sa = *(const float4*)&att_src[col4];
    float4 da = *(const float4*)&att_dst[col4];
#pragma unroll
    for (int i = 0; i < 4; i++) {
        float ps = acc[i][0] * sa.x + acc[i][1] * sa.y + acc[i][2] * sa.z + acc[i][3] * sa.w;
        float pd = acc[i][0] * da.x + acc[i][1] * da.y + acc[i][2] * da.z + acc[i][3] * da.w;
#pragma unroll
        for (int off = 8; off; off >>= 1) {
            ps += __shfl_xor(ps, off);
            pd += __shfl_xor(pd, off);
        }
        if ((t & 15) == 0) {
            a_s[row0 + row4 + i] = ps;
            a_d[row0 + row4 + i] = pd;
        }
    }
}

// ---------------- softmax + weighted gather: one wave per node, group = batch.
// a_loop (self-loop attr logit) computed in-sweep: mean(aE over incoming edges).
__global__ void gather_kernel(const int* __restrict__ rowptr, const uint2* __restrict__ csr,
                              const float* __restrict__ a_s, const float* __restrict__ a_d,
                              const uint2* __restrict__ hbf,  // [n][b][c] bf16, uint2 = 4 ch
                              const float* __restrict__ bias, float* __restrict__ out) {
    int n = blockIdx.x * (blockDim.x >> 6) + (threadIdx.x >> 6);
    if (n >= NN) return;
    int lane = threadIdx.x & 63;
    int b = lane >> 4;       // group = batch
    int t = lane & 15;       // 4-channel index within row
    int r0 = rowptr[n];
    int deg = rowptr[n + 1] - r0;
    const float* asb = a_s + (size_t)b * NN;
    float adst = a_d[(size_t)b * NN + n];

    float ds = 0.f;
    float aEs = 0.f;
    float4 acc = make_float4(0.f, 0.f, 0.f, 0.f);
    for (int base = 0; base < deg; base += 16) {
        int j = base + t;
        float ex = 0.f;
        int sreg = 0;
        if (j < deg) {
            uint2 pr = csr[r0 + j];
            sreg = (int)pr.x;
            float aev = __uint_as_float(pr.y);
            aEs += aev;
            ex = __expf(lrelu(asb[sreg] + adst + aev, 0.2f));
        }
        ds += ex;
        int cn = min(16, deg - base);
#pragma unroll 4
        for (int jj = 0; jj < cn; jj++) {
            int sl = (b << 4) + jj;
            float al = __shfl(ex, sl);
            int sj = __shfl(sreg, sl);
            uint2 hv = hbf[(size_t)sj * (NB * C / 4) + (b << 4) + t];
            acc.x += al * __uint_as_float(hv.x << 16);
            acc.y += al * __uint_as_float(hv.x & 0xFFFF0000u);
            acc.z += al * __uint_as_float(hv.y << 16);
            acc.w += al * __uint_as_float(hv.y & 0xFFFF0000u);
        }
    }
#pragma unroll
    for (int off = 8; off; off >>= 1) {
        ds += __shfl_xor(ds, off);
        aEs += __shfl_xor(aEs, off);
    }
    float a_loop = aEs / fmaxf((float)deg, 1.0f);
    float eloop = __expf(lrelu(asb[n] + adst + a_loop, 0.2f));
    float inv = 1.f / (ds + eloop);
    uint2 hv = hbf[(size_t)n * (NB * C / 4) + (b << 4) + t];
    float4 bv = ((const float4*)bias)[t];
    float4 o;
    o.x = (acc.x + eloop * __uint_as_float(hv.x << 16)) * inv + bv.x;
    o.y = (acc.y + eloop * __uint_as_float(hv.x & 0xFFFF0000u)) * inv + bv.y;
    o.z = (acc.z + eloop * __uint_as_float(hv.y << 16)) * inv + bv.z;
    o.w = (acc.w + eloop * __uint_as_float(hv.y & 0xFFFF0000u)) * inv + bv.w;
    o.x = o.x > 0.f ? o.x : __expf(o.x) - 1.f;
    o.y = o.y > 0.f ? o.y : __expf(o.y) - 1.f;
    o.z = o.z > 0.f ? o.z : __expf(o.z) - 1.f;
    o.w = o.w > 0.f ? o.w : __expf(o.w) - 1.f;
    ((float4*)out)[((size_t)b * NN + n) * 16 + t] = o;
}

extern "C" void kernel_launch(void* const* d_in, const int* in_sizes, int n_in,
                              void* d_out, int out_size, void* d_ws, size_t ws_size,
                              hipStream_t stream) {
    const float* x      = (const float*)d_in[0];
    const int* eidx     = (const int*)d_in[1];
    const float* eattr  = (const float*)d_in[2];
    const float* W1     = (const float*)d_in[3];
    const float* W2     = (const float*)d_in[4];
    const float* W      = (const float*)d_in[5];
    const float* linW   = (const float*)d_in[6];
    const float* attS   = (const float*)d_in[7];
    const float* attD   = (const float*)d_in[8];
    const float* attE   = (const float*)d_in[9];
    const float* bias   = (const float*)d_in[10];
    float* out = (float*)d_out;

    size_t off = 0;
    auto alloc = [&](size_t bytes) {
        void* p = (char*)d_ws + off;
        off += (bytes + 255) / 256 * 256;
        return p;
    };
    int* cnt      = (int*)alloc((size_t)NN * 4);
    int* wcount   = (int*)alloc((size_t)NN * 4);
    int* rowptr   = (int*)alloc((size_t)(NN + 1) * 4);
    int* bsum     = (int*)alloc(64 * 4);
    uint2* csr    = (uint2*)alloc((size_t)NE * 8);
    unsigned* hbf = (unsigned*)alloc((size_t)NN * NB * C * 2);  // bf16
    float* a_s    = (float*)alloc((size_t)NB * NN * 4);
    float* a_d    = (float*)alloc((size_t)NB * NN * 4);
    (void)ws_size; (void)n_in; (void)in_sizes; (void)out_size;

    hipMemsetAsync(cnt, 0, (size_t)NN * 4, stream);

    degree_kernel<<<(NE + 255) / 256, 256, 0, stream>>>(eidx, cnt);

    int nblk = (NN + 1023) / 1024;  // 49
    scan_block_kernel<<<nblk, 1024, 0, stream>>>(cnt, rowptr, bsum);
    scan_sums_kernel<<<1, 64, 0, stream>>>(bsum, nblk);
    scan_add_kernel<<<(NN + 1023) / 1024, 1024, 0, stream>>>(rowptr, bsum);

    // seed wcount with rowptr so the scatter atomic returns the final csr index
    hipMemcpyAsync(wcount, rowptr, (size_t)NN * 4, hipMemcpyDeviceToDevice, stream);

    edge_mlp_scatter_kernel<<<(NE / 2 + 255) / 256, 256, 0, stream>>>(
        eattr, eidx, W1, W2, linW, attE, wcount, csr);

    nodeprep_kernel<<<(NB * NN) / 64, 256, 0, stream>>>(x, W, attS, attD, hbf, a_s, a_d);

    gather_kernel<<<(NN + 3) / 4, 256, 0, stream>>>(rowptr, csr, a_s, a_d,
                                                    (const uint2*)hbf, bias, out);
}